// Round 7
// baseline (325.666 us; speedup 1.0000x reference)
//
#include <hip/hip_runtime.h>
#include <hip/hip_bf16.h>
#include <cstdint>

typedef __bf16 bf16_t;
typedef __bf16 bf16x8 __attribute__((ext_vector_type(8)));
typedef float  floatx4 __attribute__((ext_vector_type(4)));

typedef const __attribute__((address_space(1))) unsigned int* gptr_t;
typedef __attribute__((address_space(3))) unsigned int* lptr_t;

static __device__ __forceinline__ void gl2lds16(const bf16_t* g, bf16_t* l) {
  __builtin_amdgcn_global_load_lds((gptr_t)g, (lptr_t)l, 16, 0, 0);
}

// ---------------------------------------------------------------------------
// NT GEMM, producer/consumer wave-specialized (breaks the m97 barrier-drain
// plateau): 512 threads = 4 compute waves (128x128 tile, 4x4 16x16x32 MFMAs
// each) + 4 producer waves. 4-stage LDS ring (BK=32 per stage, 64 KB); sync
// via LDS atomic counters, NO __syncthreads in the K-loop -> no wave-wide
// vmcnt(0) drain. Producers: global_load_lds -> s_waitcnt vmcnt(0) (own
// loads only) -> release prod[s]. Consumers: acquire-spin prod[s], ds_read
// frags, release cons[s]. Producers overwrite stage s fill f only after
// cons[s] >= 4*f. Deadlock-free: all 8 waves co-resident, counters monotonic.
// bf16 epilogue repack uses a dedicated LDS region (no barrier needed).
// EXP_COLSUM: C=exp(alpha*acc), column sums atomicAdd'ed into global L.
// SPLIT3 (merged QKV): V chunk stored transposed (Vt[b][d][s]) directly.
// ---------------------------------------------------------------------------
template<int OUT_BF16, int HAS_BIAS, int EXP_COLSUM, int SPLIT3>
__global__ __launch_bounds__(512, 4)
void gemm_nt(const bf16_t* __restrict__ A, const bf16_t* __restrict__ Bt,
             void* __restrict__ Cv,
             const float* __restrict__ b0, const float* __restrict__ b1,
             const float* __restrict__ b2,
             float* __restrict__ L,
             int M, int N, int K, int ldC, float alpha,
             long sA, long sB, long sC,
             long co0, long co1, long co2,
             int mbShift, int ldTv, long sTv)
{
  __shared__ __align__(16) bf16_t ring[4 * 8192];   // 4 stages x (As+Bs) = 64 KB
  __shared__ __align__(16) bf16_t epi[4 * 16 * 68]; // compute-wave repack region
  __shared__ int prodf[4], consf[4];

  if (threadIdx.x < 4) { prodf[threadIdx.x] = 0; consf[threadIdx.x] = 0; }
  __syncthreads();   // the only barrier in this kernel

  const int bz = blockIdx.z;
  A  += bz * sA;
  Bt += bz * sB;

  // XCD-aware swizzle (hw round-robins id%8 across XCDs; nb%8==0 here)
  int bx = blockIdx.x, by = blockIdx.y;
  {
    const int gx = gridDim.x;
    const int nb = gx * gridDim.y;
    if ((nb & 7) == 0) {
      const int id = bx + gx * by;
      const int T  = (id & 7) * (nb >> 3) + (id >> 3);
      bx = T % gx;
      by = T / gx;
    }
  }

  const int gn0 = bx * 128;
  const int m0  = by * 128;
  const int tid  = threadIdx.x;
  const int lane = tid & 63;
  const int wave = tid >> 6;
  const int nIt  = K >> 5;

  if (wave >= 4) {
    // ---------------- producer waves ----------------
    const int p      = wave & 3;
    const int srow   = lane >> 2;
    const int schunk = (lane & 3) * 8;
    for (int it = 0; it < nIt; ++it) {
      const int s = it & 3;
      const int f = it >> 2;
      if (f > 0) {
        const int tgt = 4 * f;
        while (__hip_atomic_load(&consf[s], __ATOMIC_ACQUIRE,
                                 __HIP_MEMORY_SCOPE_WORKGROUP) < tgt)
          __builtin_amdgcn_s_sleep(1);
      }
      bf16_t* As = ring + s * 8192;
      bf16_t* Bs = As + 4096;
      const int kk = it << 5;
#pragma unroll
      for (int t = 0; t < 2; ++t) {
        const int r = p * 32 + t * 16 + srow;
        gl2lds16(A  + (long)(m0  + r) * K + kk + schunk, &As[r * 32 + schunk]);
        gl2lds16(Bt + (long)(gn0 + r) * K + kk + schunk, &Bs[r * 32 + schunk]);
      }
      __builtin_amdgcn_s_waitcnt(0x0f70);   // vmcnt(0) only (own loads)
      if (lane == 0)
        __hip_atomic_fetch_add(&prodf[s], 1, __ATOMIC_RELEASE,
                               __HIP_MEMORY_SCOPE_WORKGROUP);
    }
    return;  // producers exit; no barrier follows
  }

  // ---------------- compute waves ----------------
  const int wm   = (wave >> 1) * 64;
  const int wn   = (wave & 1) * 64;
  const int lm   = lane & 15;
  const int quad = lane >> 4;

  int n0 = gn0;
  int which = 0;
  bf16_t* Cb = (bf16_t*)Cv;
  float*  Cf = (float*)Cv;
  const float* bias = b0;
  if (SPLIT3) {
    which = gn0 >> 10;
    n0 = gn0 & 1023;
    Cb += (which == 0) ? co0 : (which == 1) ? co1 : co2;
    bias = (which == 0) ? b0 : (which == 1) ? b1 : b2;
  }

  floatx4 acc[4][4];
#pragma unroll
  for (int i = 0; i < 4; ++i)
#pragma unroll
    for (int j = 0; j < 4; ++j)
      acc[i][j] = (floatx4)(0.f);

  for (int it = 0; it < nIt; ++it) {
    const int s = it & 3;
    const int tgt = 4 * ((it >> 2) + 1);
    while (__hip_atomic_load(&prodf[s], __ATOMIC_ACQUIRE,
                             __HIP_MEMORY_SCOPE_WORKGROUP) < tgt)
      __builtin_amdgcn_s_sleep(1);
    const bf16_t* As = ring + s * 8192;
    const bf16_t* Bs = As + 4096;

    bf16x8 af[4], bfr[4];
#pragma unroll
    for (int i = 0; i < 4; ++i)
      af[i] = *(const bf16x8*)&As[(wm + i * 16 + lm) * 32 + quad * 8];
#pragma unroll
    for (int j = 0; j < 4; ++j)
      bfr[j] = *(const bf16x8*)&Bs[(wn + j * 16 + lm) * 32 + quad * 8];
    // release AFTER frag loads: lgkm drain in the fence guarantees reads done
    if (lane == 0)
      __hip_atomic_fetch_add(&consf[s], 1, __ATOMIC_RELEASE,
                             __HIP_MEMORY_SCOPE_WORKGROUP);
#pragma unroll
    for (int i = 0; i < 4; ++i)
#pragma unroll
      for (int j = 0; j < 4; ++j)
        acc[i][j] = __builtin_amdgcn_mfma_f32_16x16x32_bf16(af[i], bfr[j],
                                                            acc[i][j], 0, 0, 0);
  }

  // C/D layout: col = lane&15, row = quad*4 + r (measured m89/m91)
  if (SPLIT3 && which == 2) {
    // transposed epilogue: store Vt[b][d][s] directly (dedicated region)
    bf16_t* myT = epi + wave * (16 * 68);
    const int b  = m0 >> mbShift;
    const int s0 = m0 & ((1 << mbShift) - 1);
    const int r8 = lane >> 3;
    const int c8 = lane & 7;
#pragma unroll
    for (int j = 0; j < 4; ++j) {
      const float bv = HAS_BIAS ? bias[n0 + wn + j * 16 + lm] : 0.f;
#pragma unroll
      for (int i = 0; i < 4; ++i)
#pragma unroll
        for (int r = 0; r < 4; ++r)
          myT[lm * 68 + i * 16 + quad * 4 + r] = (bf16_t)(acc[i][j][r] + bv);
      // per-wave region + in-order DS pipe: no barrier needed
#pragma unroll
      for (int t = 0; t < 2; ++t) {
        const int nr = t * 8 + r8;
        const bf16x8 vv = *(const bf16x8*)&myT[nr * 68 + c8 * 8];
        *(bf16x8*)&Cb[(long)b * sTv + (long)(n0 + wn + j * 16 + nr) * ldTv
                      + s0 + wm + c8 * 8] = vv;
      }
    }
  } else if (OUT_BF16) {
    bf16_t* myEp = epi + wave * (16 * 68);
    const int r8 = lane >> 3;
    const int c8 = lane & 7;
    float cs[4] = {0.f, 0.f, 0.f, 0.f};
#pragma unroll
    for (int i = 0; i < 4; ++i) {
#pragma unroll
      for (int j = 0; j < 4; ++j) {
        const float bv = HAS_BIAS ? bias[n0 + wn + j * 16 + lm] : 0.f;
#pragma unroll
        for (int r = 0; r < 4; ++r) {
          float v = alpha * acc[i][j][r];
          if (EXP_COLSUM) { v = __expf(v); cs[j] += v; }
          v += bv;
          myEp[(quad * 4 + r) * 68 + j * 16 + lm] = (bf16_t)v;
        }
      }
#pragma unroll
      for (int t = 0; t < 2; ++t) {
        const int row = t * 8 + r8;
        const bf16x8 vv = *(const bf16x8*)&myEp[row * 68 + c8 * 8];
        *(bf16x8*)&Cb[bz * sC + (long)(m0 + wm + i * 16 + row) * ldC
                      + n0 + wn + c8 * 8] = vv;
      }
    }
    if (EXP_COLSUM) {
#pragma unroll
      for (int j = 0; j < 4; ++j) {
        float v = cs[j];
        v += __shfl_xor(v, 16);
        v += __shfl_xor(v, 32);
        if (quad == 0)
          atomicAdd(&L[bz * N + gn0 + wn + j * 16 + lm], v);
      }
    }
  } else {
    // fp32 out: full 64B lines already
#pragma unroll
    for (int j = 0; j < 4; ++j) {
      const int cn = n0 + wn + j * 16 + lm;
      const float bv = HAS_BIAS ? bias[n0 + wn + j * 16 + lm] : 0.f;
#pragma unroll
      for (int i = 0; i < 4; ++i) {
        const int rbase = m0 + wm + i * 16 + quad * 4;
#pragma unroll
        for (int r = 0; r < 4; ++r)
          Cf[bz * sC + (long)(rbase + r) * ldC + cn] = alpha * acc[i][j][r] + bv;
      }
    }
  }
}

// ---------------------------------------------------------------------------
// prep: one dispatch for (a) x fp32->bf16 (blocks 0..8191) and (b) the four
// 1024x1024 weight transposes (blocks 8192..12287).
// ---------------------------------------------------------------------------
__global__ __launch_bounds__(256)
void prep(const float* __restrict__ x, bf16_t* __restrict__ Xb,
          const float* __restrict__ w0, const float* __restrict__ w1,
          const float* __restrict__ w2, const float* __restrict__ w3,
          bf16_t* __restrict__ outQKV, bf16_t* __restrict__ outO)
{
  __shared__ float tile[32][33];
  const int id = blockIdx.x;
  if (id < 8192) {
    const long i = ((long)id * 256 + threadIdx.x) * 4;
    const float4 v = *(const float4*)(x + i);
    struct alignas(8) B4 { bf16_t a, b, c, d; };
    B4 o; o.a = (bf16_t)v.x; o.b = (bf16_t)v.y; o.c = (bf16_t)v.z; o.d = (bf16_t)v.w;
    *(B4*)(Xb + i) = o;
  } else {
    const int t = id - 8192;
    const int z = t >> 10;
    const int bx = t & 31, by = (t >> 5) & 31;
    const float* in = (z == 0) ? w0 : (z == 1) ? w1 : (z == 2) ? w2 : w3;
    bf16_t* out = (z < 3) ? outQKV + (long)z * 1024 * 1024 : outO;
    const int c0 = bx * 32, r0 = by * 32;
    const int tx = threadIdx.x & 31;
    const int ty = threadIdx.x >> 5;
#pragma unroll
    for (int i = 0; i < 32; i += 8)
      tile[ty + i][tx] = in[(long)(r0 + ty + i) * 1024 + (c0 + tx)];
    __syncthreads();
#pragma unroll
    for (int i = 0; i < 32; i += 8)
      out[(long)(c0 + ty + i) * 1024 + (r0 + tx)] = (bf16_t)tile[tx][ty + i];
  }
}

// Vt[b][d][s] *= 1/L[b][s]  (folds softmax denominator into V)
__global__ __launch_bounds__(256)
void scale_vt(bf16_t* __restrict__ Vt, const float* __restrict__ L, int S)
{
  const long base = ((long)blockIdx.x * blockDim.x + threadIdx.x) * 8;
  const int b  = (int)(base >> 21);
  const int s0 = (int)(base & (long)(S - 1));
  const float* Lb = L + b * S + s0;
  bf16x8 v = *(const bf16x8*)(Vt + base);
#pragma unroll
  for (int j = 0; j < 8; ++j)
    v[j] = (bf16_t)((float)v[j] / Lb[j]);
  *(bf16x8*)(Vt + base) = v;
}

// ---------------------------------------------------------------------------
extern "C" void kernel_launch(void* const* d_in, const int* in_sizes, int n_in,
                              void* d_out, int out_size, void* d_ws, size_t ws_size,
                              hipStream_t stream)
{
  const int Bz = 4, S = 2048, F = 1024, DK = 1024;
  const int M = Bz * S;

  const float* x  = (const float*)d_in[0];
  const float* Wq = (const float*)d_in[1];
  const float* bq = (const float*)d_in[2];
  const float* Wk = (const float*)d_in[3];
  const float* bk = (const float*)d_in[4];
  const float* Wv = (const float*)d_in[5];
  const float* bv = (const float*)d_in[6];
  const float* Wo = (const float*)d_in[7];
  const float* bo = (const float*)d_in[8];

  char* ws = (char*)d_ws;
  const size_t MB = 1ull << 20;
  bf16_t* Xb   = (bf16_t*)(ws + 0);        // dead after QKV gemm
  bf16_t* Sc   = (bf16_t*)(ws + 0);        // 32MB P (over dead Xb)
  bf16_t* Q    = (bf16_t*)(ws + 32 * MB);  // dead after scores gemm
  bf16_t* Ctx  = (bf16_t*)(ws + 32 * MB);
  bf16_t* Kb   = (bf16_t*)(ws + 48 * MB);
  bf16_t* Vt   = (bf16_t*)(ws + 64 * MB);  // written directly by QKV epilogue
  bf16_t* WcatT= (bf16_t*)(ws + 80 * MB);  // 6MB, dead after QKV
  float*  L    = (float*)(ws + 80 * MB);   // 32KB over dead WcatT
  bf16_t* WoT  = (bf16_t*)(ws + 86 * MB);  // 2MB

  const long coQ = 16 * MB;  // Q  at byte 32MB (bf16 elem offsets)
  const long coK = 24 * MB;  // Kb at byte 48MB
  const long coV = 32 * MB;  // Vt at byte 64MB (transposed store)

  prep<<<12288, 256, 0, stream>>>(x, Xb, Wq, Wk, Wv, Wo, WcatT, WoT);

  // merged Q/K/V projection; V chunk stored transposed as Vt[b][d][s]
  gemm_nt<1, 1, 0, 1><<<dim3(3 * DK / 128, M / 128, 1), 512, 0, stream>>>(
      Xb, WcatT, (void*)ws, bq, bk, bv, nullptr, M, 3 * DK, F, DK, 1.f,
      0, 0, 0, coQ, coK, coV, 11, S, (long)DK * S);

  // P[b][q][k] = exp(Q.K/sqrt(dk)); column sums -> L (fused, atomics)
  hipMemsetAsync(L, 0, (size_t)Bz * S * sizeof(float), stream);
  gemm_nt<1, 0, 1, 0><<<dim3(S / 128, S / 128, Bz), 512, 0, stream>>>(
      Q, Kb, Sc, nullptr, nullptr, nullptr, L, S, S, DK, S, 0.03125f,
      (long)S * DK, (long)S * DK, (long)S * S, 0, 0, 0, 0, 0, 0);

  scale_vt<<<((long)Bz * DK * S / 8) / 256, 256, 0, stream>>>(Vt, L, S);

  // ctx[b][q][d] = P[b] @ (V/L)[b]
  gemm_nt<1, 0, 0, 0><<<dim3(DK / 128, S / 128, Bz), 512, 0, stream>>>(
      Sc, Vt, Ctx, nullptr, nullptr, nullptr, nullptr, S, DK, S, DK, 1.f,
      (long)S * S, (long)S * DK, (long)S * DK, 0, 0, 0, 0, 0, 0);

  // out = ctx @ Wo + bo (fp32)
  gemm_nt<0, 1, 0, 0><<<dim3(F / 128, M / 128, 1), 512, 0, stream>>>(
      Ctx, WoT, d_out, bo, nullptr, nullptr, nullptr, M, F, DK, F, 1.f,
      0, 0, 0, 0, 0, 0, 0, 0, 0);
}

// Round 8
// 290.887 us; speedup vs baseline: 1.1196x; 1.1196x over previous
//
#include <hip/hip_runtime.h>
#include <hip/hip_bf16.h>
#include <cstdint>

typedef __bf16 bf16_t;
typedef __bf16 bf16x8 __attribute__((ext_vector_type(8)));
typedef float  floatx4 __attribute__((ext_vector_type(4)));

typedef const __attribute__((address_space(1))) unsigned int* gptr_t;
typedef __attribute__((address_space(3))) unsigned int* lptr_t;

static __device__ __forceinline__ void gl2lds16(const bf16_t* g, bf16_t* l) {
  __builtin_amdgcn_global_load_lds((gptr_t)g, (lptr_t)l, 16, 0, 0);
}

// ---------------------------------------------------------------------------
// NT GEMM: C[M,N] = f(alpha * A[M,K] * B^T) + bias[n].  (round-6 core)
// bf16 in, fp32 accumulate, 128x128 tile, 4 waves x (4x4) 16x16x32 MFMAs.
// K-loop: BK=64 as TWO BK=32 panels per barrier pair (32 KB LDS) — halves
// the vmcnt(0)+s_barrier drains (R6: 803 TF). Round-7 wave-specialization
// REGRESSED (half the MFMA waves, spin-VALU) — reverted.
// XCD swizzle v2: id&7 -> XCD gets an 8-row stripe, traversed in 4-column
// panels so BOTH the A-stripe (2 MB) and B-panel (1 MB) stay L2-resident
// (R6 counters: FETCH 74 MB vs 24 unique = B re-streaming per m-row).
// bf16 out: per-wave LDS repack unioned over panels -> full-line bf16x8.
// EXP_COLSUM: C=exp(alpha*acc), column sums atomicAdd'ed into L.
// SPLIT3 (merged QKV): V chunk stored transposed (Vt[b][d][s]) directly.
// ---------------------------------------------------------------------------
template<int OUT_BF16, int HAS_BIAS, int EXP_COLSUM, int SPLIT3>
__global__ __launch_bounds__(256, 4)
void gemm_nt(const bf16_t* __restrict__ A, const bf16_t* __restrict__ Bt,
             void* __restrict__ Cv,
             const float* __restrict__ b0, const float* __restrict__ b1,
             const float* __restrict__ b2,
             float* __restrict__ L,
             int M, int N, int K, int ldC, float alpha,
             long sA, long sB, long sC,
             long co0, long co1, long co2,
             int mbShift, int ldTv, long sTv)
{
  __shared__ __align__(16) bf16_t smem[4 * 128 * 32];  // 32 KB
  bf16_t* As0 = smem;
  bf16_t* Bs0 = smem + 4096;
  bf16_t* As1 = smem + 8192;
  bf16_t* Bs1 = smem + 12288;

  const int bz = blockIdx.z;
  A  += bz * sA;
  Bt += bz * sB;

  // XCD-aware swizzle v2: per-XCD stripe of gy/8 m-rows, walked in 4-col
  // panels (col-fastest within panel) for simultaneous A+B L2 residency.
  int bx = blockIdx.x, by = blockIdx.y;
  {
    const int gx = gridDim.x, gy = gridDim.y;
    const int nb = gx * gy;
    if (((nb & 7) == 0) && ((gx & 3) == 0) && ((gy & 7) == 0)) {
      const int id   = bx + gx * by;
      const int xcd  = id & 7;
      const int o    = id >> 3;
      const int rows = gy >> 3;          // m-rows per XCD stripe
      const int pw   = rows << 2;        // tiles per 4-col panel
      const int p    = o / pw;
      const int r    = o - p * pw;
      by = xcd * rows + (r >> 2);
      bx = (p << 2) + (r & 3);
    }
  }

  const int gn0 = bx * 128;
  const int m0  = by * 128;
  const int tid  = threadIdx.x;
  const int lane = tid & 63;
  const int wave = tid >> 6;
  const int wm   = (wave >> 1) * 64;
  const int wn   = (wave & 1) * 64;
  const int lm   = lane & 15;
  const int quad = lane >> 4;

  int n0 = gn0;
  int which = 0;
  bf16_t* Cb = (bf16_t*)Cv;
  float*  Cf = (float*)Cv;
  const float* bias = b0;
  if (SPLIT3) {
    which = gn0 >> 10;
    n0 = gn0 & 1023;
    Cb += (which == 0) ? co0 : (which == 1) ? co1 : co2;
    bias = (which == 0) ? b0 : (which == 1) ? b1 : b2;
  }

  const int srow   = lane >> 2;        // 0..15
  const int schunk = (lane & 3) * 8;   // 8 bf16 = 16B

  floatx4 acc[4][4];
#pragma unroll
  for (int i = 0; i < 4; ++i)
#pragma unroll
    for (int j = 0; j < 4; ++j)
      acc[i][j] = (floatx4)(0.f);

  for (int kk = 0; kk < K; kk += 64) {
    __syncthreads();
#pragma unroll
    for (int t = 0; t < 2; ++t) {
      const int r = wave * 32 + t * 16 + srow;
      const long ar = (long)(m0  + r) * K + kk + schunk;
      const long br = (long)(gn0 + r) * K + kk + schunk;
      gl2lds16(A  + ar,      &As0[r * 32 + schunk]);
      gl2lds16(A  + ar + 32, &As1[r * 32 + schunk]);
      gl2lds16(Bt + br,      &Bs0[r * 32 + schunk]);
      gl2lds16(Bt + br + 32, &Bs1[r * 32 + schunk]);
    }
    __syncthreads();

    {
      bf16x8 af[4], bfr[4];
#pragma unroll
      for (int i = 0; i < 4; ++i)
        af[i] = *(const bf16x8*)&As0[(wm + i * 16 + lm) * 32 + quad * 8];
#pragma unroll
      for (int j = 0; j < 4; ++j)
        bfr[j] = *(const bf16x8*)&Bs0[(wn + j * 16 + lm) * 32 + quad * 8];
#pragma unroll
      for (int i = 0; i < 4; ++i)
#pragma unroll
        for (int j = 0; j < 4; ++j)
          acc[i][j] = __builtin_amdgcn_mfma_f32_16x16x32_bf16(af[i], bfr[j],
                                                              acc[i][j], 0, 0, 0);
    }
    {
      bf16x8 af[4], bfr[4];
#pragma unroll
      for (int i = 0; i < 4; ++i)
        af[i] = *(const bf16x8*)&As1[(wm + i * 16 + lm) * 32 + quad * 8];
#pragma unroll
      for (int j = 0; j < 4; ++j)
        bfr[j] = *(const bf16x8*)&Bs1[(wn + j * 16 + lm) * 32 + quad * 8];
#pragma unroll
      for (int i = 0; i < 4; ++i)
#pragma unroll
        for (int j = 0; j < 4; ++j)
          acc[i][j] = __builtin_amdgcn_mfma_f32_16x16x32_bf16(af[i], bfr[j],
                                                              acc[i][j], 0, 0, 0);
    }
  }

  // C/D layout: col = lane&15, row = quad*4 + r (measured m89/m91)
  if (SPLIT3 && which == 2) {
    // transposed epilogue: store Vt[b][d][s] directly
    __syncthreads();
    bf16_t* myT = smem + wave * (16 * 68);
    const int b  = m0 >> mbShift;
    const int s0 = m0 & ((1 << mbShift) - 1);
    const int r8 = lane >> 3;
    const int c8 = lane & 7;
#pragma unroll
    for (int j = 0; j < 4; ++j) {
      const float bv = HAS_BIAS ? bias[n0 + wn + j * 16 + lm] : 0.f;
#pragma unroll
      for (int i = 0; i < 4; ++i)
#pragma unroll
        for (int r = 0; r < 4; ++r)
          myT[lm * 68 + i * 16 + quad * 4 + r] = (bf16_t)(acc[i][j][r] + bv);
      // per-wave region + in-order DS pipe: no barrier needed
#pragma unroll
      for (int t = 0; t < 2; ++t) {
        const int nr = t * 8 + r8;
        const bf16x8 vv = *(const bf16x8*)&myT[nr * 68 + c8 * 8];
        *(bf16x8*)&Cb[(long)b * sTv + (long)(n0 + wn + j * 16 + nr) * ldTv
                      + s0 + wm + c8 * 8] = vv;
      }
    }
  } else if (OUT_BF16) {
    __syncthreads();
    bf16_t* myEp = smem + wave * (16 * 68);
    const int r8 = lane >> 3;
    const int c8 = lane & 7;
    float cs[4] = {0.f, 0.f, 0.f, 0.f};
#pragma unroll
    for (int i = 0; i < 4; ++i) {
#pragma unroll
      for (int j = 0; j < 4; ++j) {
        const float bv = HAS_BIAS ? bias[n0 + wn + j * 16 + lm] : 0.f;
#pragma unroll
        for (int r = 0; r < 4; ++r) {
          float v = alpha * acc[i][j][r];
          if (EXP_COLSUM) { v = __expf(v); cs[j] += v; }
          v += bv;
          myEp[(quad * 4 + r) * 68 + j * 16 + lm] = (bf16_t)v;
        }
      }
#pragma unroll
      for (int t = 0; t < 2; ++t) {
        const int row = t * 8 + r8;
        const bf16x8 vv = *(const bf16x8*)&myEp[row * 68 + c8 * 8];
        *(bf16x8*)&Cb[bz * sC + (long)(m0 + wm + i * 16 + row) * ldC
                      + n0 + wn + c8 * 8] = vv;
      }
    }
    if (EXP_COLSUM) {
#pragma unroll
      for (int j = 0; j < 4; ++j) {
        float v = cs[j];
        v += __shfl_xor(v, 16);
        v += __shfl_xor(v, 32);
        if (quad == 0)
          atomicAdd(&L[bz * N + gn0 + wn + j * 16 + lm], v);
      }
    }
  } else {
    // fp32 out: full 64B lines already
#pragma unroll
    for (int j = 0; j < 4; ++j) {
      const int cn = n0 + wn + j * 16 + lm;
      const float bv = HAS_BIAS ? bias[n0 + wn + j * 16 + lm] : 0.f;
#pragma unroll
      for (int i = 0; i < 4; ++i) {
        const int rbase = m0 + wm + i * 16 + quad * 4;
#pragma unroll
        for (int r = 0; r < 4; ++r)
          Cf[bz * sC + (long)(rbase + r) * ldC + cn] = alpha * acc[i][j][r] + bv;
      }
    }
  }
}

// ---------------------------------------------------------------------------
// prep: one dispatch for (a) x fp32->bf16 (blocks 0..8191) and (b) the four
// 1024x1024 weight transposes (blocks 8192..12287).
// ---------------------------------------------------------------------------
__global__ __launch_bounds__(256)
void prep(const float* __restrict__ x, bf16_t* __restrict__ Xb,
          const float* __restrict__ w0, const float* __restrict__ w1,
          const float* __restrict__ w2, const float* __restrict__ w3,
          bf16_t* __restrict__ outQKV, bf16_t* __restrict__ outO)
{
  __shared__ float tile[32][33];
  const int id = blockIdx.x;
  if (id < 8192) {
    const long i = ((long)id * 256 + threadIdx.x) * 4;
    const float4 v = *(const float4*)(x + i);
    struct alignas(8) B4 { bf16_t a, b, c, d; };
    B4 o; o.a = (bf16_t)v.x; o.b = (bf16_t)v.y; o.c = (bf16_t)v.z; o.d = (bf16_t)v.w;
    *(B4*)(Xb + i) = o;
  } else {
    const int t = id - 8192;
    const int z = t >> 10;
    const int bx = t & 31, by = (t >> 5) & 31;
    const float* in = (z == 0) ? w0 : (z == 1) ? w1 : (z == 2) ? w2 : w3;
    bf16_t* out = (z < 3) ? outQKV + (long)z * 1024 * 1024 : outO;
    const int c0 = bx * 32, r0 = by * 32;
    const int tx = threadIdx.x & 31;
    const int ty = threadIdx.x >> 5;
#pragma unroll
    for (int i = 0; i < 32; i += 8)
      tile[ty + i][tx] = in[(long)(r0 + ty + i) * 1024 + (c0 + tx)];
    __syncthreads();
#pragma unroll
    for (int i = 0; i < 32; i += 8)
      out[(long)(c0 + ty + i) * 1024 + (r0 + tx)] = (bf16_t)tile[tx][ty + i];
  }
}

// Vt[b][d][s] *= 1/L[b][s]  (folds softmax denominator into V)
__global__ __launch_bounds__(256)
void scale_vt(bf16_t* __restrict__ Vt, const float* __restrict__ L, int S)
{
  const long base = ((long)blockIdx.x * blockDim.x + threadIdx.x) * 8;
  const int b  = (int)(base >> 21);
  const int s0 = (int)(base & (long)(S - 1));
  const float* Lb = L + b * S + s0;
  bf16x8 v = *(const bf16x8*)(Vt + base);
#pragma unroll
  for (int j = 0; j < 8; ++j)
    v[j] = (bf16_t)((float)v[j] / Lb[j]);
  *(bf16x8*)(Vt + base) = v;
}

// ---------------------------------------------------------------------------
extern "C" void kernel_launch(void* const* d_in, const int* in_sizes, int n_in,
                              void* d_out, int out_size, void* d_ws, size_t ws_size,
                              hipStream_t stream)
{
  const int Bz = 4, S = 2048, F = 1024, DK = 1024;
  const int M = Bz * S;

  const float* x  = (const float*)d_in[0];
  const float* Wq = (const float*)d_in[1];
  const float* bq = (const float*)d_in[2];
  const float* Wk = (const float*)d_in[3];
  const float* bk = (const float*)d_in[4];
  const float* Wv = (const float*)d_in[5];
  const float* bv = (const float*)d_in[6];
  const float* Wo = (const float*)d_in[7];
  const float* bo = (const float*)d_in[8];

  char* ws = (char*)d_ws;
  const size_t MB = 1ull << 20;
  bf16_t* Xb   = (bf16_t*)(ws + 0);        // dead after QKV gemm
  bf16_t* Sc   = (bf16_t*)(ws + 0);        // 32MB P (over dead Xb)
  bf16_t* Q    = (bf16_t*)(ws + 32 * MB);  // dead after scores gemm
  bf16_t* Ctx  = (bf16_t*)(ws + 32 * MB);
  bf16_t* Kb   = (bf16_t*)(ws + 48 * MB);
  bf16_t* Vt   = (bf16_t*)(ws + 64 * MB);  // written directly by QKV epilogue
  bf16_t* WcatT= (bf16_t*)(ws + 80 * MB);  // 6MB, dead after QKV
  float*  L    = (float*)(ws + 80 * MB);   // 32KB over dead WcatT
  bf16_t* WoT  = (bf16_t*)(ws + 86 * MB);  // 2MB

  const long coQ = 16 * MB;  // Q  at byte 32MB (bf16 elem offsets)
  const long coK = 24 * MB;  // Kb at byte 48MB
  const long coV = 32 * MB;  // Vt at byte 64MB (transposed store)

  prep<<<12288, 256, 0, stream>>>(x, Xb, Wq, Wk, Wv, Wo, WcatT, WoT);

  // merged Q/K/V projection; V chunk stored transposed as Vt[b][d][s]
  gemm_nt<1, 1, 0, 1><<<dim3(3 * DK / 128, M / 128, 1), 256, 0, stream>>>(
      Xb, WcatT, (void*)ws, bq, bk, bv, nullptr, M, 3 * DK, F, DK, 1.f,
      0, 0, 0, coQ, coK, coV, 11, S, (long)DK * S);

  // P[b][q][k] = exp(Q.K/sqrt(dk)); column sums -> L (fused, atomics)
  hipMemsetAsync(L, 0, (size_t)Bz * S * sizeof(float), stream);
  gemm_nt<1, 0, 1, 0><<<dim3(S / 128, S / 128, Bz), 256, 0, stream>>>(
      Q, Kb, Sc, nullptr, nullptr, nullptr, L, S, S, DK, S, 0.03125f,
      (long)S * DK, (long)S * DK, (long)S * S, 0, 0, 0, 0, 0, 0);

  scale_vt<<<((long)Bz * DK * S / 8) / 256, 256, 0, stream>>>(Vt, L, S);

  // ctx[b][q][d] = P[b] @ (V/L)[b]
  gemm_nt<1, 0, 0, 0><<<dim3(DK / 128, S / 128, Bz), 256, 0, stream>>>(
      Sc, Vt, Ctx, nullptr, nullptr, nullptr, nullptr, S, DK, S, DK, 1.f,
      (long)S * S, (long)S * DK, (long)S * DK, 0, 0, 0, 0, 0, 0);

  // out = ctx @ Wo + bo (fp32)
  gemm_nt<0, 1, 0, 0><<<dim3(F / 128, M / 128, 1), 256, 0, stream>>>(
      Ctx, WoT, d_out, bo, nullptr, nullptr, nullptr, M, F, DK, F, 1.f,
      0, 0, 0, 0, 0, 0, 0, 0, 0);
}

// Round 9
// 280.671 us; speedup vs baseline: 1.1603x; 1.0364x over previous
//
#include <hip/hip_runtime.h>
#include <hip/hip_bf16.h>
#include <cstdint>

typedef __bf16 bf16_t;
typedef __bf16 bf16x8 __attribute__((ext_vector_type(8)));
typedef float  floatx4 __attribute__((ext_vector_type(4)));

typedef const __attribute__((address_space(1))) unsigned int* gptr_t;
typedef __attribute__((address_space(3))) unsigned int* lptr_t;

static __device__ __forceinline__ void gl2lds16(const bf16_t* g, bf16_t* l) {
  __builtin_amdgcn_global_load_lds((gptr_t)g, (lptr_t)l, 16, 0, 0);
}

// ---------------------------------------------------------------------------
// NT GEMM: C[M,N] = f(alpha * A[M,K] * B^T) + bias[n].  (round-6 core)
// bf16 in, fp32 accumulate, 128x128 tile, 4 waves x (4x4) 16x16x32 MFMAs,
// BK=64 as two BK=32 panels per barrier pair (32 KB LDS).
// ROUND-9: XOR chunk swizzle. Old layout: ds_read_b128 frag loads at 64B row
// stride -> bank base (16*row+4*quad)%32 -> 8-WAY CONFLICT on every fragment
// read (the constant SQ_LDS_BANK_CONFLICT=6.29M). global_load_lds forbids
// padding (dest = base + lane*16), so instead LDS slot (R,c) holds GLOBAL
// chunk c ^ ((R>>1)&3); frag read for (m,q) uses LDS chunk q ^ ((m>>1)&3).
// -> 2-way conflicts only (free, m136). Coalescing unchanged (permutation
// stays within each row's 64B segment).
// XCD swizzle v2: id&7 -> XCD stripe, walked in 4-col panels (A+B L2-resident;
// R8: FETCH 74->41 MB).
// bf16 out: per-wave LDS repack unioned over panels -> full-line bf16x8.
// EXP_COLSUM: C=exp(alpha*acc), column sums atomicAdd'ed into L.
// SPLIT3 (merged QKV): V chunk stored transposed (Vt[b][d][s]) directly.
// ---------------------------------------------------------------------------
template<int OUT_BF16, int HAS_BIAS, int EXP_COLSUM, int SPLIT3>
__global__ __launch_bounds__(256, 4)
void gemm_nt(const bf16_t* __restrict__ A, const bf16_t* __restrict__ Bt,
             void* __restrict__ Cv,
             const float* __restrict__ b0, const float* __restrict__ b1,
             const float* __restrict__ b2,
             float* __restrict__ L,
             int M, int N, int K, int ldC, float alpha,
             long sA, long sB, long sC,
             long co0, long co1, long co2,
             int mbShift, int ldTv, long sTv)
{
  __shared__ __align__(16) bf16_t smem[4 * 128 * 32];  // 32 KB
  bf16_t* As0 = smem;
  bf16_t* Bs0 = smem + 4096;
  bf16_t* As1 = smem + 8192;
  bf16_t* Bs1 = smem + 12288;

  const int bz = blockIdx.z;
  A  += bz * sA;
  Bt += bz * sB;

  // XCD-aware swizzle v2
  int bx = blockIdx.x, by = blockIdx.y;
  {
    const int gx = gridDim.x, gy = gridDim.y;
    const int nb = gx * gy;
    if (((nb & 7) == 0) && ((gx & 3) == 0) && ((gy & 7) == 0)) {
      const int id   = bx + gx * by;
      const int xcd  = id & 7;
      const int o    = id >> 3;
      const int rows = gy >> 3;
      const int pw   = rows << 2;
      const int p    = o / pw;
      const int r    = o - p * pw;
      by = xcd * rows + (r >> 2);
      bx = (p << 2) + (r & 3);
    }
  }

  const int gn0 = bx * 128;
  const int m0  = by * 128;
  const int tid  = threadIdx.x;
  const int lane = tid & 63;
  const int wave = tid >> 6;
  const int wm   = (wave >> 1) * 64;
  const int wn   = (wave & 1) * 64;
  const int lm   = lane & 15;
  const int quad = lane >> 4;

  int n0 = gn0;
  int which = 0;
  bf16_t* Cb = (bf16_t*)Cv;
  float*  Cf = (float*)Cv;
  const float* bias = b0;
  if (SPLIT3) {
    which = gn0 >> 10;
    n0 = gn0 & 1023;
    Cb += (which == 0) ? co0 : (which == 1) ? co1 : co2;
    bias = (which == 0) ? b0 : (which == 1) ? b1 : b2;
  }

  // staging: lane -> (row srow, LDS chunk lane&3); global chunk XOR-swizzled
  const int srow   = lane >> 2;                       // 0..15
  const int schunk = (lane & 3) * 8;                  // LDS slot (fixed!)
  const int gchunk = ((lane & 3) ^ ((srow >> 1) & 3)) * 8;  // global source
  // fragment-read chunk permute for this lane's rows (row ≡ lm mod 16)
  const int fswz   = ((lm >> 1) & 3) * 8;

  floatx4 acc[4][4];
#pragma unroll
  for (int i = 0; i < 4; ++i)
#pragma unroll
    for (int j = 0; j < 4; ++j)
      acc[i][j] = (floatx4)(0.f);

  for (int kk = 0; kk < K; kk += 64) {
    __syncthreads();
#pragma unroll
    for (int t = 0; t < 2; ++t) {
      const int r = wave * 32 + t * 16 + srow;
      const long ar = (long)(m0  + r) * K + kk + gchunk;
      const long br = (long)(gn0 + r) * K + kk + gchunk;
      gl2lds16(A  + ar,      &As0[r * 32 + schunk]);
      gl2lds16(A  + ar + 32, &As1[r * 32 + schunk]);
      gl2lds16(Bt + br,      &Bs0[r * 32 + schunk]);
      gl2lds16(Bt + br + 32, &Bs1[r * 32 + schunk]);
    }
    __syncthreads();

    {
      bf16x8 af[4], bfr[4];
#pragma unroll
      for (int i = 0; i < 4; ++i)
        af[i] = *(const bf16x8*)&As0[(wm + i * 16 + lm) * 32 + ((quad * 8) ^ fswz)];
#pragma unroll
      for (int j = 0; j < 4; ++j)
        bfr[j] = *(const bf16x8*)&Bs0[(wn + j * 16 + lm) * 32 + ((quad * 8) ^ fswz)];
#pragma unroll
      for (int i = 0; i < 4; ++i)
#pragma unroll
        for (int j = 0; j < 4; ++j)
          acc[i][j] = __builtin_amdgcn_mfma_f32_16x16x32_bf16(af[i], bfr[j],
                                                              acc[i][j], 0, 0, 0);
    }
    {
      bf16x8 af[4], bfr[4];
#pragma unroll
      for (int i = 0; i < 4; ++i)
        af[i] = *(const bf16x8*)&As1[(wm + i * 16 + lm) * 32 + ((quad * 8) ^ fswz)];
#pragma unroll
      for (int j = 0; j < 4; ++j)
        bfr[j] = *(const bf16x8*)&Bs1[(wn + j * 16 + lm) * 32 + ((quad * 8) ^ fswz)];
#pragma unroll
      for (int i = 0; i < 4; ++i)
#pragma unroll
        for (int j = 0; j < 4; ++j)
          acc[i][j] = __builtin_amdgcn_mfma_f32_16x16x32_bf16(af[i], bfr[j],
                                                              acc[i][j], 0, 0, 0);
    }
  }

  // C/D layout: col = lane&15, row = quad*4 + r (measured m89/m91)
  if (SPLIT3 && which == 2) {
    // transposed epilogue: store Vt[b][d][s] directly
    __syncthreads();
    bf16_t* myT = smem + wave * (16 * 68);
    const int b  = m0 >> mbShift;
    const int s0 = m0 & ((1 << mbShift) - 1);
    const int r8 = lane >> 3;
    const int c8 = lane & 7;
#pragma unroll
    for (int j = 0; j < 4; ++j) {
      const float bv = HAS_BIAS ? bias[n0 + wn + j * 16 + lm] : 0.f;
#pragma unroll
      for (int i = 0; i < 4; ++i)
#pragma unroll
        for (int r = 0; r < 4; ++r)
          myT[lm * 68 + i * 16 + quad * 4 + r] = (bf16_t)(acc[i][j][r] + bv);
      // per-wave region + in-order DS pipe: no barrier needed
#pragma unroll
      for (int t = 0; t < 2; ++t) {
        const int nr = t * 8 + r8;
        const bf16x8 vv = *(const bf16x8*)&myT[nr * 68 + c8 * 8];
        *(bf16x8*)&Cb[(long)b * sTv + (long)(n0 + wn + j * 16 + nr) * ldTv
                      + s0 + wm + c8 * 8] = vv;
      }
    }
  } else if (OUT_BF16) {
    __syncthreads();
    bf16_t* myEp = smem + wave * (16 * 68);
    const int r8 = lane >> 3;
    const int c8 = lane & 7;
    float cs[4] = {0.f, 0.f, 0.f, 0.f};
#pragma unroll
    for (int i = 0; i < 4; ++i) {
#pragma unroll
      for (int j = 0; j < 4; ++j) {
        const float bv = HAS_BIAS ? bias[n0 + wn + j * 16 + lm] : 0.f;
#pragma unroll
        for (int r = 0; r < 4; ++r) {
          float v = alpha * acc[i][j][r];
          if (EXP_COLSUM) { v = __expf(v); cs[j] += v; }
          v += bv;
          myEp[(quad * 4 + r) * 68 + j * 16 + lm] = (bf16_t)v;
        }
      }
#pragma unroll
      for (int t = 0; t < 2; ++t) {
        const int row = t * 8 + r8;
        const bf16x8 vv = *(const bf16x8*)&myEp[row * 68 + c8 * 8];
        *(bf16x8*)&Cb[bz * sC + (long)(m0 + wm + i * 16 + row) * ldC
                      + n0 + wn + c8 * 8] = vv;
      }
    }
    if (EXP_COLSUM) {
#pragma unroll
      for (int j = 0; j < 4; ++j) {
        float v = cs[j];
        v += __shfl_xor(v, 16);
        v += __shfl_xor(v, 32);
        if (quad == 0)
          atomicAdd(&L[bz * N + gn0 + wn + j * 16 + lm], v);
      }
    }
  } else {
    // fp32 out: full 64B lines already
#pragma unroll
    for (int j = 0; j < 4; ++j) {
      const int cn = n0 + wn + j * 16 + lm;
      const float bv = HAS_BIAS ? bias[n0 + wn + j * 16 + lm] : 0.f;
#pragma unroll
      for (int i = 0; i < 4; ++i) {
        const int rbase = m0 + wm + i * 16 + quad * 4;
#pragma unroll
        for (int r = 0; r < 4; ++r)
          Cf[bz * sC + (long)(rbase + r) * ldC + cn] = alpha * acc[i][j][r] + bv;
      }
    }
  }
}

// ---------------------------------------------------------------------------
// prep: one dispatch for (a) x fp32->bf16 (blocks 0..8191) and (b) the four
// 1024x1024 weight transposes (blocks 8192..12287).
// ---------------------------------------------------------------------------
__global__ __launch_bounds__(256)
void prep(const float* __restrict__ x, bf16_t* __restrict__ Xb,
          const float* __restrict__ w0, const float* __restrict__ w1,
          const float* __restrict__ w2, const float* __restrict__ w3,
          bf16_t* __restrict__ outQKV, bf16_t* __restrict__ outO)
{
  __shared__ float tile[32][33];
  const int id = blockIdx.x;
  if (id < 8192) {
    const long i = ((long)id * 256 + threadIdx.x) * 4;
    const float4 v = *(const float4*)(x + i);
    struct alignas(8) B4 { bf16_t a, b, c, d; };
    B4 o; o.a = (bf16_t)v.x; o.b = (bf16_t)v.y; o.c = (bf16_t)v.z; o.d = (bf16_t)v.w;
    *(B4*)(Xb + i) = o;
  } else {
    const int t = id - 8192;
    const int z = t >> 10;
    const int bx = t & 31, by = (t >> 5) & 31;
    const float* in = (z == 0) ? w0 : (z == 1) ? w1 : (z == 2) ? w2 : w3;
    bf16_t* out = (z < 3) ? outQKV + (long)z * 1024 * 1024 : outO;
    const int c0 = bx * 32, r0 = by * 32;
    const int tx = threadIdx.x & 31;
    const int ty = threadIdx.x >> 5;
#pragma unroll
    for (int i = 0; i < 32; i += 8)
      tile[ty + i][tx] = in[(long)(r0 + ty + i) * 1024 + (c0 + tx)];
    __syncthreads();
#pragma unroll
    for (int i = 0; i < 32; i += 8)
      out[(long)(c0 + ty + i) * 1024 + (r0 + tx)] = (bf16_t)tile[tx][ty + i];
  }
}

// Vt[b][d][s] *= 1/L[b][s]  (folds softmax denominator into V)
__global__ __launch_bounds__(256)
void scale_vt(bf16_t* __restrict__ Vt, const float* __restrict__ L, int S)
{
  const long base = ((long)blockIdx.x * blockDim.x + threadIdx.x) * 8;
  const int b  = (int)(base >> 21);
  const int s0 = (int)(base & (long)(S - 1));
  const float* Lb = L + b * S + s0;
  bf16x8 v = *(const bf16x8*)(Vt + base);
#pragma unroll
  for (int j = 0; j < 8; ++j)
    v[j] = (bf16_t)((float)v[j] / Lb[j]);
  *(bf16x8*)(Vt + base) = v;
}

// ---------------------------------------------------------------------------
extern "C" void kernel_launch(void* const* d_in, const int* in_sizes, int n_in,
                              void* d_out, int out_size, void* d_ws, size_t ws_size,
                              hipStream_t stream)
{
  const int Bz = 4, S = 2048, F = 1024, DK = 1024;
  const int M = Bz * S;

  const float* x  = (const float*)d_in[0];
  const float* Wq = (const float*)d_in[1];
  const float* bq = (const float*)d_in[2];
  const float* Wk = (const float*)d_in[3];
  const float* bk = (const float*)d_in[4];
  const float* Wv = (const float*)d_in[5];
  const float* bv = (const float*)d_in[6];
  const float* Wo = (const float*)d_in[7];
  const float* bo = (const float*)d_in[8];

  char* ws = (char*)d_ws;
  const size_t MB = 1ull << 20;
  bf16_t* Xb   = (bf16_t*)(ws + 0);        // dead after QKV gemm
  bf16_t* Sc   = (bf16_t*)(ws + 0);        // 32MB P (over dead Xb)
  bf16_t* Q    = (bf16_t*)(ws + 32 * MB);  // dead after scores gemm
  bf16_t* Ctx  = (bf16_t*)(ws + 32 * MB);
  bf16_t* Kb   = (bf16_t*)(ws + 48 * MB);
  bf16_t* Vt   = (bf16_t*)(ws + 64 * MB);  // written directly by QKV epilogue
  bf16_t* WcatT= (bf16_t*)(ws + 80 * MB);  // 6MB, dead after QKV
  float*  L    = (float*)(ws + 80 * MB);   // 32KB over dead WcatT
  bf16_t* WoT  = (bf16_t*)(ws + 86 * MB);  // 2MB

  const long coQ = 16 * MB;  // Q  at byte 32MB (bf16 elem offsets)
  const long coK = 24 * MB;  // Kb at byte 48MB
  const long coV = 32 * MB;  // Vt at byte 64MB (transposed store)

  prep<<<12288, 256, 0, stream>>>(x, Xb, Wq, Wk, Wv, Wo, WcatT, WoT);

  // merged Q/K/V projection; V chunk stored transposed as Vt[b][d][s]
  gemm_nt<1, 1, 0, 1><<<dim3(3 * DK / 128, M / 128, 1), 256, 0, stream>>>(
      Xb, WcatT, (void*)ws, bq, bk, bv, nullptr, M, 3 * DK, F, DK, 1.f,
      0, 0, 0, coQ, coK, coV, 11, S, (long)DK * S);

  // P[b][q][k] = exp(Q.K/sqrt(dk)); column sums -> L (fused, atomics)
  hipMemsetAsync(L, 0, (size_t)Bz * S * sizeof(float), stream);
  gemm_nt<1, 0, 1, 0><<<dim3(S / 128, S / 128, Bz), 256, 0, stream>>>(
      Q, Kb, Sc, nullptr, nullptr, nullptr, L, S, S, DK, S, 0.03125f,
      (long)S * DK, (long)S * DK, (long)S * S, 0, 0, 0, 0, 0, 0);

  scale_vt<<<((long)Bz * DK * S / 8) / 256, 256, 0, stream>>>(Vt, L, S);

  // ctx[b][q][d] = P[b] @ (V/L)[b]
  gemm_nt<1, 0, 0, 0><<<dim3(DK / 128, S / 128, Bz), 256, 0, stream>>>(
      Sc, Vt, Ctx, nullptr, nullptr, nullptr, nullptr, S, DK, S, DK, 1.f,
      (long)S * S, (long)S * DK, (long)S * DK, 0, 0, 0, 0, 0, 0);

  // out = ctx @ Wo + bo (fp32)
  gemm_nt<0, 1, 0, 0><<<dim3(F / 128, M / 128, 1), 256, 0, stream>>>(
      Ctx, WoT, d_out, bo, nullptr, nullptr, nullptr, M, F, DK, F, 1.f,
      0, 0, 0, 0, 0, 0, 0, 0, 0);
}